// Round 11
// baseline (101.506 us; speedup 1.0000x reference)
//
#include <hip/hip_runtime.h>
#include <hip/hip_bf16.h>

#define ALPHA 0.2f

typedef unsigned short ushort_t;
typedef unsigned int   uint_t;
typedef unsigned short ushort8 __attribute__((ext_vector_type(8)));
typedef uint_t uintv4 __attribute__((ext_vector_type(4)));
typedef float f32x4 __attribute__((ext_vector_type(4)));
typedef __bf16 bf16x8 __attribute__((ext_vector_type(8)));

// float -> bf16 bits, round-to-nearest-even (values are finite here)
__device__ __forceinline__ ushort_t f2bf(float f) {
  unsigned u = __float_as_uint(f);
  u += 0x7fffu + ((u >> 16) & 1u);
  return (ushort_t)(u >> 16);
}

// ---------------------------------------------------------------------------
// Kernel P: pack graph (0/1 floats) into a bitmask (4 MB -> 128 KB).
// Block 0 additionally computes u1 = W^T a1, u2 = W^T a2 (s = X.u).
// ---------------------------------------------------------------------------
__global__ __launch_bounds__(256) void gat_pack_kernel(
    const float* __restrict__ graph, const float* __restrict__ W,
    const float* __restrict__ avec, uint_t* __restrict__ gmask,
    float* __restrict__ u)
{
  const int row = blockIdx.x, t = threadIdx.x;
  __shared__ uint_t nibs[256];
  float4 g = ((const float4*)(graph + (size_t)row * 1024))[t];
  uint_t nib = (g.x != 0.f ? 1u : 0u) | (g.y != 0.f ? 2u : 0u) |
               (g.z != 0.f ? 4u : 0u) | (g.w != 0.f ? 8u : 0u);
  nibs[t] = nib;
  __syncthreads();
  if (t < 32) {
    uint_t wd = 0;
#pragma unroll
    for (int k = 0; k < 8; ++k) wd |= nibs[t * 8 + k] << (4 * k);
    gmask[(size_t)row * 32 + t] = wd;
  }
  if (row == 0 && t < 128) {             // u: 128 outputs (u1[64] | u2[64])
    const int k  = t & 63;
    const int ao = (t >> 6) * 128;
    float a0 = 0.f, a1 = 0.f, a2 = 0.f, a3 = 0.f;
    for (int d = 0; d < 128; d += 4) {
      a0 = fmaf(avec[ao + d + 0], W[(d + 0) * 64 + k], a0);
      a1 = fmaf(avec[ao + d + 1], W[(d + 1) * 64 + k], a1);
      a2 = fmaf(avec[ao + d + 2], W[(d + 2) * 64 + k], a2);
      a3 = fmaf(avec[ao + d + 3], W[(d + 3) * 64 + k], a3);
    }
    u[t] = (a0 + a1) + (a2 + a3);
  }
}

// ---------------------------------------------------------------------------
// Kernel A: h = X * W^T (fp32), hT[b][d][n] bf16, s1 = X.u1, s2 = X.u2.
// 32 n-rows per block, grid 1024 -> 4 blocks/CU (occupancy fix vs R10).
// ---------------------------------------------------------------------------
__global__ __launch_bounds__(256) void gat_h_kernel(
    const float* __restrict__ inp, const float* __restrict__ W,
    const float* __restrict__ uvec, ushort_t* __restrict__ hT,
    float* __restrict__ s1, float* __restrict__ s2)
{
  const int b  = blockIdx.x >> 5;        // 32 chunks of 32 rows per batch
  const int n0 = (blockIdx.x & 31) << 5;
  const int t  = threadIdx.x;
  const int d  = t & 127;                // output channel
  const int nh = t >> 7;                 // which 16-row half

  __shared__ float    x_lds[32][68];     // 8.7 KB (pad: breaks bank striding)
  __shared__ float    u_lds[128];
  __shared__ ushort_t h_tile[128][40];   // 10 KB (80 B rows, 16B-aligned)

  float wreg[64];
  {
    const float4* wrow = (const float4*)(W + d * 64);
#pragma unroll
    for (int k = 0; k < 16; ++k) {
      float4 v = wrow[k];
      wreg[4*k+0] = v.x; wreg[4*k+1] = v.y; wreg[4*k+2] = v.z; wreg[4*k+3] = v.w;
    }
  }
  if (t < 128) u_lds[t] = uvec[t];

  {
    const float4* xsrc = (const float4*)(inp + ((size_t)b * 1024 + n0) * 64);
#pragma unroll
    for (int k = 0; k < 2; ++k) {
      const int g = k * 256 + t;         // 0..511 float4s
      const int n = g >> 4, c = g & 15;
      *(float4*)&x_lds[n][c * 4] = xsrc[g];
    }
  }
  __syncthreads();

  // h tile: thread (d, nh) computes 16 rows; X reads are wave-broadcast.
  for (int r = 0; r < 16; ++r) {
    const int n = nh * 16 + r;
    const float* xr = &x_lds[n][0];
    float ax = 0.f, ay = 0.f, az = 0.f, aw = 0.f;
#pragma unroll
    for (int k = 0; k < 16; ++k) {
      float4 xv = *(const float4*)&xr[4 * k];
      ax = fmaf(wreg[4*k+0], xv.x, ax);
      ay = fmaf(wreg[4*k+1], xv.y, ay);
      az = fmaf(wreg[4*k+2], xv.z, az);
      aw = fmaf(wreg[4*k+3], xv.w, aw);
    }
    h_tile[d][n] = f2bf((ax + ay) + (az + aw));
  }

  // s1/s2: thread t<64 -> row n=t&31, half t>>5
  if (t < 64) {
    const int n = t & 31, which = t >> 5;
    const float* xr = &x_lds[n][0];
    const float* uu = &u_lds[which * 64];
    float a0 = 0.f, a1 = 0.f, a2 = 0.f, a3 = 0.f;
#pragma unroll
    for (int k = 0; k < 16; ++k) {
      float4 xv = *(const float4*)&xr[4 * k];
      a0 = fmaf(xv.x, uu[4*k+0], a0);
      a1 = fmaf(xv.y, uu[4*k+1], a1);
      a2 = fmaf(xv.z, uu[4*k+2], a2);
      a3 = fmaf(xv.w, uu[4*k+3], a3);
    }
    const float sv = (a0 + a1) + (a2 + a3);
    if (which == 0) s1[(size_t)b * 1024 + n0 + n] = sv;
    else            s2[(size_t)b * 1024 + n0 + n] = sv;
  }
  __syncthreads();

  // coalesced bf16 hT writes: 2 iters x 256 chunks of 16 B
#pragma unroll
  for (int it = 0; it < 2; ++it) {
    const int idx = it * 256 + t;        // 0..511
    const int d2  = idx >> 2;
    const int ch  = (idx & 3) * 8;
    ushort8 v = *(const ushort8*)&h_tile[d2][ch];
    *(ushort8*)(hT + ((size_t)b * 128 + d2) * 1024 + n0 + ch) = v;
  }
}

// ---------------------------------------------------------------------------
// Kernel B: fused masked softmax + attention GEMM, BARRIER-FREE main loop.
// Grid 1024 (XCD-swizzled), block = 4 waves, 32 i-rows x 128 d.
// XCD swizzle: b = (bid&7)*4 + (bid>>3)/32 -> all 32 blocks of a batch land
// on one XCD (RR dispatch) -> its 256 KB hT slab is fetched once and stays
// in that XCD's L2 (correctness-neutral remap).
// Wave (ih,dh) owns 16 rows x 64 d.  Per j-32 tile:
//   - A-fragments (P) computed IN REGISTERS: lane l = row ib+(l&15),
//     k-slots (l>>4)*8+e  (verified convention; B uses the same k mapping)
//   - B-fragments loaded DIRECTLY from global hT (L2-hit), prefetched 1 ahead
//   - 4 MFMA; den per-lane, completed by 2x shfl_xor.
// No LDS exchange, no __syncthreads in the loop.
// Prepass (all-LDS bitmask): exact masked row max -> Mi -> den >= 1.
// C/D layout: col = lane&15, row = (lane>>4)*4 + reg  [m89-verified].
// den from bf16-ROUNDED p via v_cvt_pk_bf16_f32 (RNE, matches f2bf).
// ---------------------------------------------------------------------------
__global__ __launch_bounds__(256) void gat_attn_kernel(
    const uint_t* __restrict__ gmask, const ushort_t* __restrict__ hT,
    const float* __restrict__ s1g, const float* __restrict__ s2g,
    const float* __restrict__ bias, float* __restrict__ out)
{
  const int bid = blockIdx.x;          // 0..1023
  const int b   = (bid & 7) * 4 + ((bid >> 3) >> 5);  // 0..31, XCD-grouped
  const int ic  = (bid >> 3) & 31;     // 0..31
  const int i0  = ic << 5;             // 32 rows per block
  const int t   = threadIdx.x;
  const int w   = t >> 6;
  const int l   = t & 63;
  const int ih  = w >> 1;              // i-half (16 rows)
  const int dh  = w & 1;               // d-half (64 cols)
  const int rl  = l & 15;              // lane's row / B d-row index
  const int js  = (l >> 4) * 8;        // k-chunk within the 32-tile

  __shared__ float  s2_lds[1024];      // 4 KB
  __shared__ uint_t mask_lds[32][33];  // 4.2 KB (pad: conflict-free)
  __shared__ float  red_part[32][8];
  __shared__ float  red_row[32];

  ((float4*)s2_lds)[t] = ((const float4*)(s2g + (size_t)b * 1024))[t];
  {  // stage 32 rows x 32 mask words (256 uint4, one per thread)
    uint4 mv = ((const uint4*)(gmask + (size_t)i0 * 32))[t];
    const int mr = t >> 3, mc = (t & 7) * 4;
    mask_lds[mr][mc + 0] = mv.x; mask_lds[mr][mc + 1] = mv.y;
    mask_lds[mr][mc + 2] = mv.z; mask_lds[mr][mc + 3] = mv.w;
  }
  __syncthreads();

  // ---- prepass: exact masked row max over 32 rows (all-LDS) ----
  {
    const int irow = t >> 3, bo = (t & 7) * 4;
    float mx = -1e30f;
    for (int jt = 0; jt < 32; ++jt) {
      const uint_t wd = mask_lds[irow][jt] >> bo;
      const float4 sA = *(const float4*)(s2_lds + jt * 32 + bo);
      if (wd & 1u) mx = fmaxf(mx, sA.x);
      if (wd & 2u) mx = fmaxf(mx, sA.y);
      if (wd & 4u) mx = fmaxf(mx, sA.z);
      if (wd & 8u) mx = fmaxf(mx, sA.w);
    }
    red_part[irow][t & 7] = mx;
  }
  __syncthreads();
  if (t < 32) {
    float m = red_part[t][0];
#pragma unroll
    for (int k = 1; k < 8; ++k) m = fmaxf(m, red_part[t][k]);
    red_row[t] = m;
  }
  __syncthreads();

  const int ib = ih * 16;              // wave's row base within the block
  const float s1v = s1g[(size_t)b * 1024 + i0 + ib + rl];
  const float tm  = s1v + red_row[ib + rl];
  const float Mi  = tm > 0.f ? tm : ALPHA * tm;   // exact row max of lrelu

  // B-fragment base: d = dh*64 + ds*16 + rl, j-chunk js
  const ushort_t* hb =
      hT + (size_t)b * 128 * 1024 + (size_t)(dh * 64 + rl) * 1024 + js;

  f32x4 c[4];
#pragma unroll
  for (int ds = 0; ds < 4; ++ds) c[ds] = f32x4{0.f, 0.f, 0.f, 0.f};
  float den = 0.f;

  ushort8 bv[4], nb[4];
#pragma unroll
  for (int ds = 0; ds < 4; ++ds)
    bv[ds] = *(const ushort8*)(hb + (size_t)ds * 16 * 1024);

#pragma unroll 4
  for (int jt = 0; jt < 32; ++jt) {
    const int j0 = jt * 32;
    const int jn = (jt + 1 < 32) ? j0 + 32 : j0;   // clamped prefetch
#pragma unroll
    for (int ds = 0; ds < 4; ++ds)
      nb[ds] = *(const ushort8*)(hb + (size_t)ds * 16 * 1024 + jn);

    const uint_t wd = mask_lds[ib + rl][jt] >> js;
    const float4 sA = *(const float4*)(s2_lds + j0 + js);
    const float4 sB = *(const float4*)(s2_lds + j0 + js + 4);
    const float sv[8] = {sA.x, sA.y, sA.z, sA.w, sB.x, sB.y, sB.z, sB.w};
    float p[8];
#pragma unroll
    for (int e = 0; e < 8; ++e) {
      const float te = s1v + sv[e];
      const float v  = fmaxf(te, ALPHA * te);        // leaky relu
      p[e] = (((wd >> e) & 1u) && v != 0.f) ? __expf(v - Mi) : 0.f;
    }
    uint_t pk[4];
#pragma unroll
    for (int q = 0; q < 4; ++q) {
      asm("v_cvt_pk_bf16_f32 %0, %1, %2"
          : "=v"(pk[q]) : "v"(p[2 * q]), "v"(p[2 * q + 1]));
      den += __uint_as_float(pk[q] << 16) +
             __uint_as_float(pk[q] & 0xffff0000u);
    }
    const bf16x8 av =
        __builtin_bit_cast(bf16x8, (uintv4){pk[0], pk[1], pk[2], pk[3]});
#pragma unroll
    for (int ds = 0; ds < 4; ++ds) {
      const bf16x8 bvv = __builtin_bit_cast(bf16x8, bv[ds]);
      c[ds] = __builtin_amdgcn_mfma_f32_16x16x32_bf16(av, bvv, c[ds], 0, 0, 0);
    }
#pragma unroll
    for (int ds = 0; ds < 4; ++ds) bv[ds] = nb[ds];
  }

  // complete den across the 4 k-groups (lanes with same l&15)
  den += __shfl_xor(den, 16);
  den += __shfl_xor(den, 32);

#pragma unroll
  for (int ds = 0; ds < 4; ++ds) {
    const int col = dh * 64 + ds * 16 + rl;
    const float bc = bias[col];
#pragma unroll
    for (int r = 0; r < 4; ++r) {
      const int rr   = (l >> 4) * 4 + r;       // 0..15 within wave tile
      const int row  = ib + rr;
      const float dr = __shfl(den, rr);        // lane rr holds den[row]
      const float val = dr > 0.f ? c[ds][r] / dr + bc : bc;
      out[((size_t)b * 1024 + i0 + row) * 128 + col] = val;
    }
  }
}

// ---------------------------------------------------------------------------
extern "C" void kernel_launch(void* const* d_in, const int* in_sizes, int n_in,
                              void* d_out, int out_size, void* d_ws, size_t ws_size,
                              hipStream_t stream) {
  (void)in_sizes; (void)n_in; (void)out_size; (void)ws_size;
  const float* inp   = (const float*)d_in[0];   // (32,1024,64) f32
  const float* graph = (const float*)d_in[1];   // (1024,1024)  f32
  const float* W     = (const float*)d_in[2];   // (128,64)     f32
  const float* bias  = (const float*)d_in[3];   // (128,)       f32
  const float* avec  = (const float*)d_in[4];   // (256,1)      f32
  float* out = (float*)d_out;                   // (32,1024,128) f32

  // workspace: hT bf16 8 MB | s1 128 KB | s2 128 KB | u 4 KB | gmask 128 KB
  char* ws = (char*)d_ws;
  ushort_t* hT = (ushort_t*)ws;
  float* s1    = (float*)(ws + (size_t)8 * 1024 * 1024);
  float* s2    = s1 + 32 * 1024;
  float* u     = s2 + 32 * 1024;
  uint_t* gm   = (uint_t*)(ws + (size_t)8 * 1024 * 1024 + 512 * 1024);

  gat_pack_kernel<<<1024, 256, 0, stream>>>(graph, W, avec, gm, u);
  gat_h_kernel<<<1024, 256, 0, stream>>>(inp, W, u, hT, s1, s2);
  gat_attn_kernel<<<1024, 256, 0, stream>>>(gm, hT, s1, s2, bias, out);
}